// Round 11
// baseline (447.259 us; speedup 1.0000x reference)
//
#include <hip/hip_runtime.h>
#include <math.h>

#define PLANE 16384   // 128*128
#define NPLANES 512   // B(128) * C(4)
#define MP 136        // LDS pitch in shorts (272B = 17*16 -> b128 aligned, 2-way-free T-stores)

typedef __attribute__((ext_vector_type(8))) short bf16x8;
typedef __attribute__((ext_vector_type(4))) float f32x4;
typedef __attribute__((ext_vector_type(4))) unsigned short ushort4v;

__device__ __forceinline__ unsigned short f2bf(float x) {
    union { float f; unsigned u; } a; a.f = x;
    unsigned r = a.u + 0x7FFFu + ((a.u >> 16) & 1u);
    return (unsigned short)(r >> 16);
}
__device__ __forceinline__ float bf2f(unsigned short h) {
    union { unsigned u; float f; } a; a.u = ((unsigned)h) << 16;
    return a.f;
}
__device__ __forceinline__ void split_bf16(float x, unsigned short& hi, unsigned short& lo) {
    hi = f2bf(x);
    lo = f2bf(x - bf2f(hi));
}

// One GEMM pass: D = M * H, M (128x128) in LDS row-major bf16 (hi+lo), H row-major
// bf16 in global (symmetric => B-layout transpose-immune). Wave wv owns rows
// [32wv, 32wv+32). acc[m][n] covers rows 32wv+16m+{(l>>4)*4+i}, cols 16n+(l&15).
__device__ __forceinline__ void mm_pass(const unsigned short* __restrict__ Hg,
                                        const unsigned short* __restrict__ Mhi,
                                        const unsigned short* __restrict__ Mlo,
                                        f32x4 acc[2][8], int wv, int l)
{
    const int lr = l & 15, lg = l >> 4;
#pragma unroll
    for (int m = 0; m < 2; ++m)
#pragma unroll
        for (int n = 0; n < 8; ++n)
            acc[m][n] = f32x4{0.f, 0.f, 0.f, 0.f};
#pragma unroll 1
    for (int kk = 0; kk < 4; ++kk) {
        bf16x8 ahi[2], alo[2];
#pragma unroll
        for (int m = 0; m < 2; ++m) {
            int row = wv * 32 + m * 16 + lr;
            int off = row * MP + kk * 32 + lg * 8;
            ahi[m] = *(const bf16x8*)&Mhi[off];
            alo[m] = *(const bf16x8*)&Mlo[off];
        }
#pragma unroll
        for (int n = 0; n < 8; ++n) {
            int col = n * 16 + lr;
            bf16x8 b = *(const bf16x8*)&Hg[col * 128 + kk * 32 + lg * 8];
#pragma unroll
            for (int m = 0; m < 2; ++m) {
                acc[m][n] = __builtin_amdgcn_mfma_f32_16x16x32_bf16(ahi[m], b, acc[m][n], 0, 0, 0);
                acc[m][n] = __builtin_amdgcn_mfma_f32_16x16x32_bf16(alo[m], b, acc[m][n], 0, 0, 0);
            }
        }
    }
}

// chain: stage X (row-major) -> T1=X*H (store T1^T) -> S=T1^T*H=C^T -> pointwise
// (KL, thresh; store Y^T) -> T3=Y^T*H (store T3^T) -> Z=T3^T*H -> scale/crop store.
template <bool ADDPOST>
__global__ __launch_bounds__(256) void fwht_mfma_t(
    const float* __restrict__ in, const float* __restrict__ vmat,
    const float* __restrict__ tmat, const float* __restrict__ addbuf,
    const unsigned short* __restrict__ Hg,
    float* __restrict__ outInv, float* __restrict__ klpart)  // klpart: [plane][128]
{
    __shared__ unsigned short Mhi[128 * MP];
    __shared__ unsigned short Mlo[128 * MP];
    const int tid = threadIdx.x;
    const int wv = tid >> 6, l = tid & 63;
    const int lr = l & 15, lg = l >> 4;
    const int plane = blockIdx.x;

    // ---- stage X: coalesced float4 reads, row-major bf16 hi/lo stores ----
    const float4* src4 = (const float4*)(in + (size_t)plane * PLANE);
#pragma unroll
    for (int g = 0; g < 16; ++g) {
        int i4 = g * 256 + tid;
        float4 x = src4[i4];
        int base = i4 << 2;
        int row = base >> 7, col = base & 127;
        unsigned short h0, h1, h2, h3, o0, o1, o2, o3;
        split_bf16(x.x, h0, o0); split_bf16(x.y, h1, o1);
        split_bf16(x.z, h2, o2); split_bf16(x.w, h3, o3);
        *(ushort4v*)&Mhi[row * MP + col] = ushort4v{h0, h1, h2, h3};
        *(ushort4v*)&Mlo[row * MP + col] = ushort4v{o0, o1, o2, o3};
    }
    __syncthreads();

    f32x4 acc[2][8];

    // ---- pass 1: T1 = X*H ; store T1^T ----
    mm_pass(Hg, Mhi, Mlo, acc, wv, l);
    __syncthreads();
#pragma unroll
    for (int m = 0; m < 2; ++m)
#pragma unroll
        for (int n = 0; n < 8; ++n)
#pragma unroll
            for (int i = 0; i < 4; ++i) {
                unsigned short hi, lo;
                split_bf16(acc[m][n][i], hi, lo);
                int rs = wv * 32 + m * 16 + lg * 4 + i;
                int cs = n * 16 + lr;
                Mhi[cs * MP + rs] = hi; Mlo[cs * MP + rs] = lo;
            }
    __syncthreads();

    // ---- pass 2: S = T1^T * H = C^T ; pointwise + KL ; store Y^T ----
    mm_pass(Hg, Mhi, Mlo, acc, wv, l);
    float ls[2][4];
#pragma unroll
    for (int m = 0; m < 2; ++m)
#pragma unroll
        for (int i = 0; i < 4; ++i) ls[m][i] = 0.f;
#pragma unroll
    for (int n = 0; n < 8; ++n) {
        int h = n * 16 + lr;                  // C-row
#pragma unroll
        for (int m = 0; m < 2; ++m)
#pragma unroll
            for (int i = 0; i < 4; ++i) {
                int w = wv * 32 + m * 16 + lg * 4 + i;   // C-col
                float vv = vmat[h * 128 + w];
                float tt = fabsf(tmat[h * 128 + w]);
                float y = acc[m][n][i] * vv;
                y = (fabsf(y) > tt) ? y : 0.f;
                ls[m][i] += 1.f / (1.f + __expf(-fabsf(y)));
                acc[m][n][i] = y;
            }
    }
    // KL: bin = w & 63; reduce over the 16 lanes (lr) sharing a row-group
#pragma unroll
    for (int m = 0; m < 2; ++m)
#pragma unroll
        for (int i = 0; i < 4; ++i) {
            float s = ls[m][i];
            s += __shfl_xor(s, 1); s += __shfl_xor(s, 2);
            s += __shfl_xor(s, 4); s += __shfl_xor(s, 8);
            ls[m][i] = s;
        }
    if (lr == 0) {
#pragma unroll
        for (int m = 0; m < 2; ++m)
#pragma unroll
            for (int i = 0; i < 4; ++i)
                klpart[(size_t)plane * 128 + wv * 32 + m * 16 + lg * 4 + i] = ls[m][i];
    }
    __syncthreads();
#pragma unroll
    for (int m = 0; m < 2; ++m)
#pragma unroll
        for (int n = 0; n < 8; ++n)
#pragma unroll
            for (int i = 0; i < 4; ++i) {
                unsigned short hi, lo;
                split_bf16(acc[m][n][i], hi, lo);
                int rs = wv * 32 + m * 16 + lg * 4 + i;
                int cs = n * 16 + lr;
                Mhi[rs * MP + cs] = hi; Mlo[rs * MP + cs] = lo;   // direct (Y^T row-major)
            }
    __syncthreads();

    // ---- pass 3: T3 = Y^T * H ; store T3^T ----
    mm_pass(Hg, Mhi, Mlo, acc, wv, l);
    __syncthreads();
#pragma unroll
    for (int m = 0; m < 2; ++m)
#pragma unroll
        for (int n = 0; n < 8; ++n)
#pragma unroll
            for (int i = 0; i < 4; ++i) {
                unsigned short hi, lo;
                split_bf16(acc[m][n][i], hi, lo);
                int rs = wv * 32 + m * 16 + lg * 4 + i;
                int cs = n * 16 + lr;
                Mhi[cs * MP + rs] = hi; Mlo[cs * MP + rs] = lo;
            }
    __syncthreads();

    // ---- pass 4: Z = T3^T * H ; scale, optional add, crop, store ----
    mm_pass(Hg, Mhi, Mlo, acc, wv, l);
    float* dst = outInv + (size_t)plane * PLANE;
    const float sc = 1.f / 16384.f;
#pragma unroll
    for (int m = 0; m < 2; ++m)
#pragma unroll
        for (int n = 0; n < 8; ++n)
#pragma unroll
            for (int i = 0; i < 4; ++i) {
                int rs = wv * 32 + m * 16 + lg * 4 + i;  // h
                int cs = n * 16 + lr;                    // w
                float val = acc[m][n][i] * sc;
                if (ADDPOST) val += addbuf[(size_t)plane * PLANE + rs * 128 + cs];
                dst[rs * 128 + cs] = (rs < 122 && cs < 122) ? val : 0.f;
            }
}

// ---------------- weight prep + Hadamard matrix (bf16, exact +/-1) ----------------
__global__ void prep_weights(const float* __restrict__ w3, const float* __restrict__ w4,
                             float* __restrict__ w3c, float* __restrict__ w4p,
                             unsigned short* __restrict__ Hg)
{
    int tid = blockIdx.x * 256 + threadIdx.x;
    if (tid < 784) {
        int oc = tid / 196;
        int rem = tid - oc * 196;
        int ic = rem / 49;
        int k = rem - ic * 49;
        int kh = k / 7, kw = k - kh * 7;
        w3c[(oc * 4 + ic) * 49 + k] = w3[(ic * 4 + oc) * 49 + (6 - kh) * 7 + (6 - kw)];
    }
    if (tid < 1024) {
        int u = tid & 7, t = (tid >> 3) & 7, pb = (tid >> 6) & 1, pa = (tid >> 7) & 1, ic = tid >> 8;
        int kh = 2 * t + (pa ? 0 : 1);
        int kw = 2 * u + (pb ? 0 : 1);
        w4p[tid] = w4[ic * 256 + kh * 16 + kw];
    }
    if (tid < 16384) {
        int i = tid >> 7, j = tid & 127;
        Hg[tid] = (__popc(i & j) & 1) ? 0xBF80u : 0x3F80u;
    }
}

// ---------------- conv1: 1->4, k16, s2, p1 ----------------
__global__ __launch_bounds__(256) void conv1_kernel(
    const float* __restrict__ x, const float* __restrict__ w1,
    const float* __restrict__ b1, float* __restrict__ out)
{
    __shared__ float tile[78][80];
    int tx = blockIdx.x, ty = blockIdx.y, b = blockIdx.z;
    int tid = threadIdx.x;
    const float* xp = x + (size_t)b * 65536;
    int r0g = ty * 64 - 1, c0g = tx * 64 - 1;
    for (int i = tid; i < 78 * 78; i += 256) {
        int rr = i / 78, cc = i - rr * 78;
        int gi = r0g + rr, gj = c0g + cc;
        tile[rr][cc] = (gi >= 0 && gi < 256 && gj >= 0 && gj < 256) ? xp[gi * 256 + gj] : 0.f;
    }
    __syncthreads();
    int cg = tid & 7, r = tid >> 3;
    int B = cg * 4;
    float acc[4][4];
#pragma unroll
    for (int oc = 0; oc < 4; ++oc)
#pragma unroll
        for (int c = 0; c < 4; ++c) acc[oc][c] = 0.f;
#pragma unroll 1
    for (int kh = 0; kh < 16; ++kh) {
        float win[24];
        const float* trow = &tile[2 * r + kh][2 * B];
#pragma unroll
        for (int k = 0; k < 6; ++k)
            *(float4*)&win[4 * k] = *(const float4*)&trow[4 * k];
#pragma unroll
        for (int oc = 0; oc < 4; ++oc) {
            const float* wr = w1 + oc * 256 + kh * 16;
#pragma unroll
            for (int kw = 0; kw < 16; ++kw) {
                float wv = wr[kw];
#pragma unroll
                for (int c = 0; c < 4; ++c)
                    acc[oc][c] = fmaf(win[2 * c + kw], wv, acc[oc][c]);
            }
        }
    }
    int oh = ty * 32 + r;
    int owb = tx * 32 + B;
    bool rowv = oh < 122;
#pragma unroll
    for (int oc = 0; oc < 4; ++oc) {
        float bv = b1[oc];
        float4 res;
        res.x = (rowv && owb + 0 < 122) ? acc[oc][0] + bv : 0.f;
        res.y = (rowv && owb + 1 < 122) ? acc[oc][1] + bv : 0.f;
        res.z = (rowv && owb + 2 < 122) ? acc[oc][2] + bv : 0.f;
        res.w = (rowv && owb + 3 < 122) ? acc[oc][3] + bv : 0.f;
        *(float4*)&out[(((size_t)b * 4 + oc) << 14) + (oh << 7) + owb] = res;
    }
}

// ---------------- 7x7 conv, 4->4, pad 3 ----------------
__global__ __launch_bounds__(256) void conv7_kernel(
    const float* __restrict__ in, const float* __restrict__ w,
    const float* __restrict__ bias, const float* __restrict__ skip,
    float* __restrict__ out)
{
    __shared__ float tile[4][38][40];
    int tx = blockIdx.x, ty = blockIdx.y, b = blockIdx.z;
    int tid = threadIdx.x;
    int r0g = ty * 32 - 3, c0g = tx * 32 - 3;
    for (int i = tid; i < 4 * 38 * 38; i += 256) {
        int ic = i / 1444;
        int rem = i - ic * 1444;
        int rr = rem / 38, cc = rem - rr * 38;
        int gi = r0g + rr, gj = c0g + cc;
        float v = 0.f;
        if (gi >= 0 && gi < 128 && gj >= 0 && gj < 128)
            v = in[(((size_t)b * 4 + ic) << 14) + (gi << 7) + gj];
        tile[ic][rr][cc] = v;
    }
    __syncthreads();
    int cg = tid & 7, r = tid >> 3;
    int B = cg * 4;
    float acc[4][4];
#pragma unroll
    for (int oc = 0; oc < 4; ++oc)
#pragma unroll
        for (int c = 0; c < 4; ++c) acc[oc][c] = 0.f;
#pragma unroll 1
    for (int ic = 0; ic < 4; ++ic) {
#pragma unroll 1
        for (int kh = 0; kh < 7; ++kh) {
            float win[12];
            const float* trow = &tile[ic][r + kh][B];
#pragma unroll
            for (int k = 0; k < 3; ++k)
                *(float4*)&win[4 * k] = *(const float4*)&trow[4 * k];
#pragma unroll
            for (int oc = 0; oc < 4; ++oc) {
                const float* wr = w + (oc * 4 + ic) * 49 + kh * 7;
#pragma unroll
                for (int kw = 0; kw < 7; ++kw) {
                    float wv = wr[kw];
#pragma unroll
                    for (int c = 0; c < 4; ++c)
                        acc[oc][c] = fmaf(win[c + kw], wv, acc[oc][c]);
                }
            }
        }
    }
    int oh = ty * 32 + r;
    int owb = tx * 32 + B;
    bool rowv = oh < 122;
#pragma unroll
    for (int oc = 0; oc < 4; ++oc) {
        size_t o = (((size_t)b * 4 + oc) << 14) + (oh << 7) + owb;
        float4 sv = make_float4(0.f, 0.f, 0.f, 0.f);
        if (skip) sv = *(const float4*)&skip[o];
        float bv = bias[oc];
        float4 res;
        res.x = (rowv && owb + 0 < 122) ? acc[oc][0] + bv + sv.x : 0.f;
        res.y = (rowv && owb + 1 < 122) ? acc[oc][1] + bv + sv.y : 0.f;
        res.z = (rowv && owb + 2 < 122) ? acc[oc][2] + bv + sv.z : 0.f;
        res.w = (rowv && owb + 3 < 122) ? acc[oc][3] + bv + sv.w : 0.f;
        *(float4*)&out[o] = res;
    }
}

// ---------------- convT4: 4->1, k16, s2, p1, parity-decomposed; then * x ----------------
#define CT_HALF(T, ROW, PA)                                                    \
    _Pragma("unroll")                                                          \
    for (int pb = 0; pb < 2; ++pb) {                                           \
        const float* w8 = wp + (((ic * 2 + (PA)) * 2 + pb) * 8 + (T)) * 8;     \
        _Pragma("unroll")                                                      \
        for (int u = 0; u < 8; ++u) {                                          \
            float wv = w8[u];                                                  \
            _Pragma("unroll")                                                  \
            for (int c = 0; c < 4; ++c)                                        \
                acc[PA][pb][c] = fmaf(ROW[8 + c + pb - u], wv, acc[PA][pb][c]);\
        }                                                                      \
    }

__global__ __launch_bounds__(256) void convt4_kernel(
    const float* __restrict__ in, const float* __restrict__ wp,
    const float* __restrict__ bias, const float* __restrict__ xin,
    float* __restrict__ out)
{
    __shared__ float tile[4][40][44];
    int tx = blockIdx.x, ty = blockIdx.y, b = blockIdx.z;
    int tid = threadIdx.x;
    int A0 = ty * 32, B0 = tx * 32;
    int r0g = A0 - 7, c0g = B0 - 8;
    for (int i = tid; i < 4 * 40 * 44; i += 256) {
        int ic = i / 1760;
        int rem = i - ic * 1760;
        int rr = rem / 44, cc = rem - rr * 44;
        int gi = r0g + rr, gj = c0g + cc;
        float v = 0.f;
        if (gi >= 0 && gi < 128 && gj >= 0 && gj < 128)
            v = in[(((size_t)b * 4 + ic) << 14) + (gi << 7) + gj];
        tile[ic][rr][cc] = v;
    }
    __syncthreads();
    int cg = tid & 7, ra = tid >> 3;
    float acc[2][2][4];
#pragma unroll
    for (int pa = 0; pa < 2; ++pa)
#pragma unroll
        for (int pb = 0; pb < 2; ++pb)
#pragma unroll
            for (int c = 0; c < 4; ++c) acc[pa][pb][c] = 0.f;
#pragma unroll 1
    for (int ic = 0; ic < 4; ++ic) {
        float bufA[16], bufB[16];
#pragma unroll
        for (int k = 0; k < 4; ++k)
            *(float4*)&bufB[4 * k] = *(const float4*)&tile[ic][ra + 8][4 * cg + 4 * k];
#pragma unroll 1
        for (int t2 = 0; t2 < 8; t2 += 2) {
#pragma unroll
            for (int k = 0; k < 4; ++k)
                *(float4*)&bufA[4 * k] = *(const float4*)&tile[ic][ra + 7 - t2][4 * cg + 4 * k];
            CT_HALF(t2, bufA, 0)
            CT_HALF(t2, bufB, 1)
#pragma unroll
            for (int k = 0; k < 4; ++k)
                *(float4*)&bufB[4 * k] = *(const float4*)&tile[ic][ra + 6 - t2][4 * cg + 4 * k];
            CT_HALF(t2 + 1, bufB, 0)
            CT_HALF(t2 + 1, bufA, 1)
        }
    }
    int oh0 = 2 * (A0 + ra);
    int owb = 2 * (B0 + 4 * cg);
    float bv = bias[0];
#pragma unroll
    for (int pa = 0; pa < 2; ++pa) {
        size_t o = (size_t)b * 65536 + (size_t)(oh0 + pa) * 256 + owb;
        float4 x0 = *(const float4*)&xin[o];
        float4 x1 = *(const float4*)&xin[o + 4];
        float4 r0, r1;
        r0.x = (acc[pa][0][0] + bv) * x0.x;
        r0.y = (acc[pa][1][0] + bv) * x0.y;
        r0.z = (acc[pa][0][1] + bv) * x0.z;
        r0.w = (acc[pa][1][1] + bv) * x0.w;
        r1.x = (acc[pa][0][2] + bv) * x1.x;
        r1.y = (acc[pa][1][2] + bv) * x1.y;
        r1.z = (acc[pa][0][3] + bv) * x1.z;
        r1.w = (acc[pa][1][3] + bv) * x1.w;
        *(float4*)&out[o] = r0;
        *(float4*)&out[o + 4] = r1;
    }
}

// ---------------- TV loss (vectorized, per-block partial) ----------------
__global__ __launch_bounds__(256) void tv_kernel(
    const float* __restrict__ out, float* __restrict__ tvpart)
{
    const float4* out4 = (const float4*)out;
    __shared__ float red[256];
    int tid = threadIdx.x;
    float local = 0.f;
    const int total4 = 128 * 65536 / 4;
    for (int i4 = blockIdx.x * 256 + tid; i4 < total4; i4 += gridDim.x * 256) {
        float4 a = out4[i4];
        int i = i4 << 2;
        local += fabsf(a.y - a.x) + fabsf(a.z - a.y) + fabsf(a.w - a.z);
        if ((i & 255) != 252) local += fabsf(out[i + 4] - a.w);
        if ((i & 65535) < 65280) {
            float4 c = out4[i4 + 64];
            local += fabsf(c.x - a.x) + fabsf(c.y - a.y) + fabsf(c.z - a.z) + fabsf(c.w - a.w);
        }
    }
    red[tid] = local;
    __syncthreads();
    for (int s = 128; s > 0; s >>= 1) {
        if (tid < s) red[tid] += red[tid + s];
        __syncthreads();
    }
    if (tid == 0) tvpart[blockIdx.x] = red[0];
}

// ---------------- stage-1 reduce: KL [3][512][128] -> [3][16][64]; TV [2048] -> [1] ----------------
__global__ __launch_bounds__(256) void reduce1_kernel(
    const float* __restrict__ klpart, const float* __restrict__ tvpart,
    float* __restrict__ klred, float* __restrict__ tvred)
{
    int bid = blockIdx.x;
    int tid = threadIdx.x;
    if (bid < 48) {
        int layer = bid >> 4, chunk = bid & 15;
        int sub = tid >> 6, t = tid & 63;
        const float* base = klpart + (size_t)layer * 65536;
        float s = 0.f;
        for (int p = sub; p < 32; p += 4) {
            const float* r = base + (size_t)(chunk * 32 + p) * 128;
            s += r[t] + r[64 + t];
        }
        __shared__ float red[4][64];
        red[sub][t] = s;
        __syncthreads();
        if (tid < 64)
            klred[(layer * 16 + chunk) * 64 + tid] =
                red[0][tid] + red[1][tid] + red[2][tid] + red[3][tid];
    } else {
        __shared__ float red[256];
        float s = 0.f;
        for (int i = tid; i < 2048; i += 256) s += tvpart[i];
        red[tid] = s;
        __syncthreads();
        for (int st = 128; st > 0; st >>= 1) {
            if (tid < st) red[tid] += red[tid + st];
            __syncthreads();
        }
        if (tid == 0) tvred[0] = red[0];
    }
}

// ---------------- stage-2 finalize ----------------
__global__ __launch_bounds__(64) void finalize2_kernel(
    const float* __restrict__ klred, const float* __restrict__ tvred,
    float* __restrict__ lossout)
{
    int t = threadIdx.x;
    float p = 1.f / (1.f + __expf(-0.001f));
    float term = 0.f;
#pragma unroll
    for (int l = 0; l < 3; ++l) {
        float q = 0.f;
#pragma unroll
        for (int c = 0; c < 16; ++c)
            q += klred[(l * 16 + c) * 64 + t];
        float qm = q * (1.f / 131072.f);
        term += p * logf(p / qm) + (1.f - p) * logf((1.f - p) / (1.f - qm));
    }
#pragma unroll
    for (int off = 32; off > 0; off >>= 1)
        term += __shfl_down(term, off);
    if (t == 0)
        lossout[0] = 0.05f * tvred[0] / 8388608.f + 0.1f * term;
}

extern "C" void kernel_launch(void* const* d_in, const int* in_sizes, int n_in,
                              void* d_out, int out_size, void* d_ws, size_t ws_size,
                              hipStream_t stream) {
    (void)in_sizes; (void)n_in; (void)out_size; (void)ws_size;
    const float* x  = (const float*)d_in[0];
    const float* v1 = (const float*)d_in[2];
    const float* T1 = (const float*)d_in[3];
    const float* v2 = (const float*)d_in[4];
    const float* T2 = (const float*)d_in[5];
    const float* v3 = (const float*)d_in[6];
    const float* T3 = (const float*)d_in[7];
    const float* w1 = (const float*)d_in[8];
    const float* b1 = (const float*)d_in[9];
    const float* w2 = (const float*)d_in[10];
    const float* b2 = (const float*)d_in[11];
    const float* w3 = (const float*)d_in[12];
    const float* b3 = (const float*)d_in[13];
    const float* w4 = (const float*)d_in[14];
    const float* b4 = (const float*)d_in[15];
    float* out = (float*)d_out;

    float* W0 = (float*)d_ws;
    float* W1 = W0 + (size_t)NPLANES * PLANE;
    float* W2 = W1 + (size_t)NPLANES * PLANE;
    float* klpart = W2 + (size_t)NPLANES * PLANE; // [3][512][128] = 196608 floats
    float* tvpart = klpart + 3 * 512 * 128;        // [2048]
    float* klred  = tvpart + 2048;                  // [3][16][64]
    float* tvred  = klred + 3072;                   // [1]
    float* w3c = tvred + 64;                        // 784
    float* w4p = w3c + 784;                         // 1024
    unsigned short* Hg = (unsigned short*)(w4p + 1024); // 16384 ushort (32KB)
    float* x10buf = out;                            // reuse d_out region as x10 scratch

    prep_weights<<<64, 256, 0, stream>>>(w3, w4, w3c, w4p, Hg);
    // x1 (padded) -> W0
    conv1_kernel<<<dim3(4, 4, 128), 256, 0, stream>>>(x, w1, b1, W0);
    // KL1 partials; x9 = crop(ifwht(x6)) -> W1
    fwht_mfma_t<false><<<NPLANES, 256, 0, stream>>>(W0, v1, T1, nullptr, Hg, W1, klpart);
    // x10 -> d_out scratch
    conv7_kernel<<<dim3(4, 4, 128), 256, 0, stream>>>(W1, w2, b2, nullptr, x10buf);
    // KL2 partials; x18 -> W0
    fwht_mfma_t<false><<<NPLANES, 256, 0, stream>>>(x10buf, v2, T2, nullptr, Hg, W0, klpart + 65536);
    // x19 = convT3(x18) + x10 -> W2
    conv7_kernel<<<dim3(4, 4, 128), 256, 0, stream>>>(W0, w3c, b3, x10buf, W2);
    // KL3 partials; x27 = crop(ifwht(x24)) + x9 -> W0
    fwht_mfma_t<true><<<NPLANES, 256, 0, stream>>>(W2, v3, T3, W1, Hg, W0, klpart + 2 * 65536);
    // out = convT4(x27) * x
    convt4_kernel<<<dim3(4, 4, 128), 256, 0, stream>>>(W0, w4p, b4, x, out);
    // TV partials
    tv_kernel<<<2048, 256, 0, stream>>>(out, tvpart);
    // reduce + finalize
    reduce1_kernel<<<49, 256, 0, stream>>>(klpart, tvpart, klred, tvred);
    finalize2_kernel<<<1, 64, 0, stream>>>(klred, tvred, out + 8388608);
}

// Round 12
// 370.116 us; speedup vs baseline: 1.2084x; 1.2084x over previous
//
#include <hip/hip_runtime.h>
#include <math.h>

#define PLANE 16384   // 128*128
#define NPLANES 512   // B(128) * C(4)

// ---------------- in-register 2D FWHT-128x128 across a 256-thread block ----------------
// Thread (W = tid>>6, L = tid&63) holds v[g*4+c] = plane[h][w],
//   h = W*32 + (L>>5)*16 + g   (g in [0,16))
//   w = (L&31)*4 + c           (c in [0,4))
__device__ __forceinline__ void fwht2d_reg(float* __restrict__ v, float* __restrict__ xch,
                                           int W, int L) {
    // w bits 0-1: in-register
#pragma unroll
    for (int m = 1; m <= 2; m <<= 1) {
#pragma unroll
        for (int r = 0; r < 64; ++r) {
            if (!(r & m)) {
                int s = r | m;
                float a = v[r], b = v[s];
                v[r] = a + b; v[s] = a - b;
            }
        }
    }
    // w bits 2-6 and h bit 4: cross-lane shuffle stages
#pragma unroll
    for (int m = 1; m <= 32; m <<= 1) {
        float sg = (L & m) ? -1.f : 1.f;
#pragma unroll
        for (int r = 0; r < 64; ++r) {
            float p = __shfl_xor(v[r], m);
            v[r] = fmaf(sg, v[r], p);
        }
    }
    // h bits 0-3: in-register
#pragma unroll
    for (int m = 4; m <= 32; m <<= 1) {
#pragma unroll
        for (int r = 0; r < 64; ++r) {
            if (!(r & m)) {
                int s = r | m;
                float a = v[r], b = v[s];
                v[r] = a + b; v[s] = a - b;
            }
        }
    }
    // h bits 5-6 (wave index): LDS exchange, 2 stages x 2 reg-chunks, conflict-free layout
#pragma unroll
    for (int mw = 1; mw <= 2; mw <<= 1) {
        int Wp = W ^ mw;
        float sg = (W & mw) ? -1.f : 1.f;
#pragma unroll
        for (int half = 0; half < 2; ++half) {
            __syncthreads();
#pragma unroll
            for (int j = 0; j < 32; ++j)
                xch[(j * 4 + W) * 64 + L] = v[half * 32 + j];
            __syncthreads();
#pragma unroll
            for (int j = 0; j < 32; ++j) {
                float p = xch[(j * 4 + Wp) * 64 + L];
                v[half * 32 + j] = fmaf(sg, v[half * 32 + j], p);
            }
        }
    }
}

// FWHT2 -> *v -> hard-thresh (KL partials) -> iFWHT2 -> (optional +addbuf) -> crop store
template <bool ADDPOST>
__global__ __launch_bounds__(256) void fwht_kernel_t(
    const float* __restrict__ in, const float* __restrict__ vmat,
    const float* __restrict__ tmat, const float* __restrict__ addbuf,
    float* __restrict__ outInv, float* __restrict__ klpart)
{
    __shared__ float xch[32 * 256]; // 32 KiB
    const int tid = threadIdx.x;
    const int W = tid >> 6, L = tid & 63;
    const int plane = blockIdx.x;
    const int hbase = W * 32 + ((L >> 5) << 4);
    const int wbase = (L & 31) << 2;
    const float* src = in + (size_t)plane * PLANE;

    float v[64];
#pragma unroll
    for (int g = 0; g < 16; ++g) {
        float4 t = *(const float4*)&src[(hbase + g) * 128 + wbase];
        v[4 * g] = t.x; v[4 * g + 1] = t.y; v[4 * g + 2] = t.z; v[4 * g + 3] = t.w;
    }

    fwht2d_reg(v, xch, W, L);

    // pointwise: *vmat, hard-threshold, KL accumulate
    float ls0 = 0.f, ls1 = 0.f, ls2 = 0.f, ls3 = 0.f;
#pragma unroll
    for (int g = 0; g < 16; ++g) {
        int rowoff = (hbase + g) * 128 + wbase;
        float4 vm = *(const float4*)&vmat[rowoff];
        float4 tm = *(const float4*)&tmat[rowoff];
        float y0 = v[4 * g]     * vm.x;
        float y1 = v[4 * g + 1] * vm.y;
        float y2 = v[4 * g + 2] * vm.z;
        float y3 = v[4 * g + 3] * vm.w;
        y0 = (fabsf(y0) > fabsf(tm.x)) ? y0 : 0.f;
        y1 = (fabsf(y1) > fabsf(tm.y)) ? y1 : 0.f;
        y2 = (fabsf(y2) > fabsf(tm.z)) ? y2 : 0.f;
        y3 = (fabsf(y3) > fabsf(tm.w)) ? y3 : 0.f;
        ls0 += 1.f / (1.f + __expf(-fabsf(y0)));
        ls1 += 1.f / (1.f + __expf(-fabsf(y1)));
        ls2 += 1.f / (1.f + __expf(-fabsf(y2)));
        ls3 += 1.f / (1.f + __expf(-fabsf(y3)));
        v[4 * g] = y0; v[4 * g + 1] = y1; v[4 * g + 2] = y2; v[4 * g + 3] = y3;
    }
    // KL bins: bin = w%64 = (L&15)*4 + c. Reduce lanes sharing (L&15), then one
    // coalesced float4 store per wave into a private partial row (NO atomics).
#pragma unroll
    for (int m = 16; m <= 32; m <<= 1) {
        ls0 += __shfl_xor(ls0, m);
        ls1 += __shfl_xor(ls1, m);
        ls2 += __shfl_xor(ls2, m);
        ls3 += __shfl_xor(ls3, m);
    }
    if (L < 16) {
        float4 o; o.x = ls0; o.y = ls1; o.z = ls2; o.w = ls3;
        *(float4*)&klpart[(size_t)(plane * 4 + W) * 64 + 4 * L] = o;
    }

    fwht2d_reg(v, xch, W, L);

    // scale 1/16384, optional add (post-inverse, by linearity), crop to 122x122, store
    float* dst = outInv + (size_t)plane * PLANE;
    const float s = 1.f / 16384.f;
#pragma unroll
    for (int g = 0; g < 16; ++g) {
        int h = hbase + g;
        int rowoff = h * 128 + wbase;
        bool rv = h < 122;
        float4 ad = make_float4(0.f, 0.f, 0.f, 0.f);
        if (ADDPOST) ad = *(const float4*)&addbuf[(size_t)plane * PLANE + rowoff];
        float4 o;
        o.x = (rv && wbase + 0 < 122) ? fmaf(v[4 * g],     s, ad.x) : 0.f;
        o.y = (rv && wbase + 1 < 122) ? fmaf(v[4 * g + 1], s, ad.y) : 0.f;
        o.z = (rv && wbase + 2 < 122) ? fmaf(v[4 * g + 2], s, ad.z) : 0.f;
        o.w = (rv && wbase + 3 < 122) ? fmaf(v[4 * g + 3], s, ad.w) : 0.f;
        *(float4*)&dst[rowoff] = o;
    }
}

// ---------------- weight prep: canonicalize w3 (transposed 7x7) and w4 (convT 16x16 s2) ----------------
__global__ void prep_weights(const float* __restrict__ w3, const float* __restrict__ w4,
                             float* __restrict__ w3c, float* __restrict__ w4p)
{
    int tid = blockIdx.x * 256 + threadIdx.x;
    if (tid < 784) {
        int oc = tid / 196;
        int rem = tid - oc * 196;
        int ic = rem / 49;
        int k = rem - ic * 49;
        int kh = k / 7, kw = k - kh * 7;
        w3c[(oc * 4 + ic) * 49 + k] = w3[(ic * 4 + oc) * 49 + (6 - kh) * 7 + (6 - kw)];
    }
    if (tid < 1024) {
        // layout [ic:2][pa:1][pb:1][t:3][u:3]
        int u = tid & 7, t = (tid >> 3) & 7, pb = (tid >> 6) & 1, pa = (tid >> 7) & 1, ic = tid >> 8;
        int kh = 2 * t + (pa ? 0 : 1);
        int kw = 2 * u + (pb ? 0 : 1);
        w4p[tid] = w4[ic * 256 + kh * 16 + kw];
    }
}

// ---------------- conv1: 1->4, k16, s2, p1 : x[B,1,256,256] -> [B,4,128,128] padded ----------------
// Parity-split LDS tile kills the 16-way bank conflict of the stride-2 window read:
// input col (2*lx+kw) -> tile[kw&1][row][lx + (kw>>1)], pitch 44 -> windows (6r+cg) mod 8.
__global__ __launch_bounds__(256) void conv1_kernel(
    const float* __restrict__ x, const float* __restrict__ w1,
    const float* __restrict__ b1, float* __restrict__ out)
{
    __shared__ float tile[2][78][44];
    int tx = blockIdx.x, ty = blockIdx.y, b = blockIdx.z;
    int tid = threadIdx.x;
    const float* xp = x + (size_t)b * 65536;
    int r0g = ty * 64 - 1, c0g = tx * 64 - 1;
    for (int i = tid; i < 78 * 78; i += 256) {
        int rr = i / 78, cc = i - rr * 78;
        int gi = r0g + rr, gj = c0g + cc;
        float v = (gi >= 0 && gi < 256 && gj >= 0 && gj < 256) ? xp[gi * 256 + gj] : 0.f;
        tile[cc & 1][rr][cc >> 1] = v;
    }
    __syncthreads();
    int cg = tid & 7, r = tid >> 3;
    int B = cg * 4;
    float acc[4][4];
#pragma unroll
    for (int oc = 0; oc < 4; ++oc)
#pragma unroll
        for (int c = 0; c < 4; ++c) acc[oc][c] = 0.f;
#pragma unroll 1
    for (int kh = 0; kh < 16; ++kh) {
        float win[2][12];
        const float* te = &tile[0][2 * r + kh][B];
        const float* to = &tile[1][2 * r + kh][B];
#pragma unroll
        for (int k = 0; k < 3; ++k) {
            *(float4*)&win[0][4 * k] = *(const float4*)&te[4 * k];
            *(float4*)&win[1][4 * k] = *(const float4*)&to[4 * k];
        }
#pragma unroll
        for (int oc = 0; oc < 4; ++oc) {
            const float* wr = w1 + oc * 256 + kh * 16;
#pragma unroll
            for (int kw = 0; kw < 16; ++kw) {
                float wv = wr[kw];
                const float* wp8 = win[kw & 1];
                int q = kw >> 1;
#pragma unroll
                for (int c = 0; c < 4; ++c)
                    acc[oc][c] = fmaf(wp8[c + q], wv, acc[oc][c]);
            }
        }
    }
    int oh = ty * 32 + r;
    int owb = tx * 32 + B;
    bool rowv = oh < 122;
#pragma unroll
    for (int oc = 0; oc < 4; ++oc) {
        float bv = b1[oc];
        float4 res;
        res.x = (rowv && owb + 0 < 122) ? acc[oc][0] + bv : 0.f;
        res.y = (rowv && owb + 1 < 122) ? acc[oc][1] + bv : 0.f;
        res.z = (rowv && owb + 2 < 122) ? acc[oc][2] + bv : 0.f;
        res.w = (rowv && owb + 3 < 122) ? acc[oc][3] + bv : 0.f;
        *(float4*)&out[(((size_t)b * 4 + oc) << 14) + (oh << 7) + owb] = res;
    }
}

// ---------------- 7x7 conv, 4->4, pad 3, canonical weights [oc][ic][kh][kw], optional skip ----------------
__global__ __launch_bounds__(256) void conv7_kernel(
    const float* __restrict__ in, const float* __restrict__ w,
    const float* __restrict__ bias, const float* __restrict__ skip,
    float* __restrict__ out)
{
    __shared__ float tile[4][38][40];
    int tx = blockIdx.x, ty = blockIdx.y, b = blockIdx.z;
    int tid = threadIdx.x;
    int r0g = ty * 32 - 3, c0g = tx * 32 - 3;
    for (int i = tid; i < 4 * 38 * 38; i += 256) {
        int ic = i / 1444;
        int rem = i - ic * 1444;
        int rr = rem / 38, cc = rem - rr * 38;
        int gi = r0g + rr, gj = c0g + cc;
        float v = 0.f;
        if (gi >= 0 && gi < 128 && gj >= 0 && gj < 128)
            v = in[(((size_t)b * 4 + ic) << 14) + (gi << 7) + gj];
        tile[ic][rr][cc] = v;
    }
    __syncthreads();
    int cg = tid & 7, r = tid >> 3;
    int B = cg * 4;
    float acc[4][4];
#pragma unroll
    for (int oc = 0; oc < 4; ++oc)
#pragma unroll
        for (int c = 0; c < 4; ++c) acc[oc][c] = 0.f;
#pragma unroll 1
    for (int ic = 0; ic < 4; ++ic) {
#pragma unroll 1
        for (int kh = 0; kh < 7; ++kh) {
            float win[12];
            const float* trow = &tile[ic][r + kh][B];
#pragma unroll
            for (int k = 0; k < 3; ++k)
                *(float4*)&win[4 * k] = *(const float4*)&trow[4 * k];
#pragma unroll
            for (int oc = 0; oc < 4; ++oc) {
                const float* wr = w + (oc * 4 + ic) * 49 + kh * 7;
#pragma unroll
                for (int kw = 0; kw < 7; ++kw) {
                    float wv = wr[kw];
#pragma unroll
                    for (int c = 0; c < 4; ++c)
                        acc[oc][c] = fmaf(win[c + kw], wv, acc[oc][c]);
                }
            }
        }
    }
    int oh = ty * 32 + r;
    int owb = tx * 32 + B;
    bool rowv = oh < 122;
#pragma unroll
    for (int oc = 0; oc < 4; ++oc) {
        size_t o = (((size_t)b * 4 + oc) << 14) + (oh << 7) + owb;
        float4 sv = make_float4(0.f, 0.f, 0.f, 0.f);
        if (skip) sv = *(const float4*)&skip[o];
        float bv = bias[oc];
        float4 res;
        res.x = (rowv && owb + 0 < 122) ? acc[oc][0] + bv + sv.x : 0.f;
        res.y = (rowv && owb + 1 < 122) ? acc[oc][1] + bv + sv.y : 0.f;
        res.z = (rowv && owb + 2 < 122) ? acc[oc][2] + bv + sv.z : 0.f;
        res.w = (rowv && owb + 3 < 122) ? acc[oc][3] + bv + sv.w : 0.f;
        *(float4*)&out[o] = res;
    }
}

// ---------------- convT4: 4->1, k16, s2, p1, parity-decomposed; then * x ----------------
#define CT_HALF(T, ROW, PA)                                                    \
    _Pragma("unroll")                                                          \
    for (int pb = 0; pb < 2; ++pb) {                                           \
        const float* w8 = wp + (((ic * 2 + (PA)) * 2 + pb) * 8 + (T)) * 8;     \
        _Pragma("unroll")                                                      \
        for (int u = 0; u < 8; ++u) {                                          \
            float wv = w8[u];                                                  \
            _Pragma("unroll")                                                  \
            for (int c = 0; c < 4; ++c)                                        \
                acc[PA][pb][c] = fmaf(ROW[8 + c + pb - u], wv, acc[PA][pb][c]);\
        }                                                                      \
    }

__global__ __launch_bounds__(256) void convt4_kernel(
    const float* __restrict__ in, const float* __restrict__ wp,
    const float* __restrict__ bias, const float* __restrict__ xin,
    float* __restrict__ out)
{
    __shared__ float tile[4][40][44];
    int tx = blockIdx.x, ty = blockIdx.y, b = blockIdx.z;
    int tid = threadIdx.x;
    int A0 = ty * 32, B0 = tx * 32;
    int r0g = A0 - 7, c0g = B0 - 8;
    for (int i = tid; i < 4 * 40 * 44; i += 256) {
        int ic = i / 1760;
        int rem = i - ic * 1760;
        int rr = rem / 44, cc = rem - rr * 44;
        int gi = r0g + rr, gj = c0g + cc;
        float v = 0.f;
        if (gi >= 0 && gi < 128 && gj >= 0 && gj < 128)
            v = in[(((size_t)b * 4 + ic) << 14) + (gi << 7) + gj];
        tile[ic][rr][cc] = v;
    }
    __syncthreads();
    int cg = tid & 7, ra = tid >> 3;
    float acc[2][2][4];
#pragma unroll
    for (int pa = 0; pa < 2; ++pa)
#pragma unroll
        for (int pb = 0; pb < 2; ++pb)
#pragma unroll
            for (int c = 0; c < 4; ++c) acc[pa][pb][c] = 0.f;
#pragma unroll 1
    for (int ic = 0; ic < 4; ++ic) {
        float bufA[16], bufB[16];
#pragma unroll
        for (int k = 0; k < 4; ++k)
            *(float4*)&bufB[4 * k] = *(const float4*)&tile[ic][ra + 8][4 * cg + 4 * k];
#pragma unroll 1
        for (int t2 = 0; t2 < 8; t2 += 2) {
#pragma unroll
            for (int k = 0; k < 4; ++k)
                *(float4*)&bufA[4 * k] = *(const float4*)&tile[ic][ra + 7 - t2][4 * cg + 4 * k];
            CT_HALF(t2, bufA, 0)
            CT_HALF(t2, bufB, 1)
#pragma unroll
            for (int k = 0; k < 4; ++k)
                *(float4*)&bufB[4 * k] = *(const float4*)&tile[ic][ra + 6 - t2][4 * cg + 4 * k];
            CT_HALF(t2 + 1, bufB, 0)
            CT_HALF(t2 + 1, bufA, 1)
        }
    }
    int oh0 = 2 * (A0 + ra);
    int owb = 2 * (B0 + 4 * cg);
    float bv = bias[0];
#pragma unroll
    for (int pa = 0; pa < 2; ++pa) {
        size_t o = (size_t)b * 65536 + (size_t)(oh0 + pa) * 256 + owb;
        float4 x0 = *(const float4*)&xin[o];
        float4 x1 = *(const float4*)&xin[o + 4];
        float4 r0, r1;
        r0.x = (acc[pa][0][0] + bv) * x0.x;
        r0.y = (acc[pa][1][0] + bv) * x0.y;
        r0.z = (acc[pa][0][1] + bv) * x0.z;
        r0.w = (acc[pa][1][1] + bv) * x0.w;
        r1.x = (acc[pa][0][2] + bv) * x1.x;
        r1.y = (acc[pa][1][2] + bv) * x1.y;
        r1.z = (acc[pa][0][3] + bv) * x1.z;
        r1.w = (acc[pa][1][3] + bv) * x1.w;
        *(float4*)&out[o] = r0;
        *(float4*)&out[o + 4] = r1;
    }
}

// ---------------- TV loss (vectorized, per-block partial, no atomics) ----------------
__global__ __launch_bounds__(256) void tv_kernel(
    const float* __restrict__ out, float* __restrict__ tvpart)
{
    const float4* out4 = (const float4*)out;
    __shared__ float red[256];
    int tid = threadIdx.x;
    float local = 0.f;
    const int total4 = 128 * 65536 / 4;
    for (int i4 = blockIdx.x * 256 + tid; i4 < total4; i4 += gridDim.x * 256) {
        float4 a = out4[i4];
        int i = i4 << 2;
        local += fabsf(a.y - a.x) + fabsf(a.z - a.y) + fabsf(a.w - a.z);
        if ((i & 255) != 252) local += fabsf(out[i + 4] - a.w);
        if ((i & 65535) < 65280) {
            float4 c = out4[i4 + 64];
            local += fabsf(c.x - a.x) + fabsf(c.y - a.y) + fabsf(c.z - a.z) + fabsf(c.w - a.w);
        }
    }
    red[tid] = local;
    __syncthreads();
    for (int s = 128; s > 0; s >>= 1) {
        if (tid < s) red[tid] += red[tid + s];
        __syncthreads();
    }
    if (tid == 0) tvpart[blockIdx.x] = red[0];
}

// ---------------- stage-1 reduce: KL partials [3][2048][64] -> [3][16][64]; TV [2048] -> [1] ----------------
__global__ __launch_bounds__(256) void reduce1_kernel(
    const float* __restrict__ klpart, const float* __restrict__ tvpart,
    float* __restrict__ klred, float* __restrict__ tvred)
{
    int bid = blockIdx.x;
    int tid = threadIdx.x;
    if (bid < 48) {
        int layer = bid >> 4, chunk = bid & 15;
        int sub = tid >> 6, t = tid & 63;
        const float* base = klpart + (size_t)layer * 131072 + (size_t)chunk * 128 * 64;
        float s = 0.f;
        for (int r = sub; r < 128; r += 4)
            s += base[r * 64 + t];
        __shared__ float red[4][64];
        red[sub][t] = s;
        __syncthreads();
        if (tid < 64)
            klred[(layer * 16 + chunk) * 64 + tid] =
                red[0][tid] + red[1][tid] + red[2][tid] + red[3][tid];
    } else {
        __shared__ float red[256];
        float s = 0.f;
        for (int i = tid; i < 2048; i += 256) s += tvpart[i];
        red[tid] = s;
        __syncthreads();
        for (int st = 128; st > 0; st >>= 1) {
            if (tid < st) red[tid] += red[tid + st];
            __syncthreads();
        }
        if (tid == 0) tvred[0] = red[0];
    }
}

// ---------------- stage-2 finalize: [3][16][64] + tv -> loss ----------------
__global__ __launch_bounds__(64) void finalize2_kernel(
    const float* __restrict__ klred, const float* __restrict__ tvred,
    float* __restrict__ lossout)
{
    int t = threadIdx.x;
    float p = 1.f / (1.f + __expf(-0.001f));
    float term = 0.f;
#pragma unroll
    for (int l = 0; l < 3; ++l) {
        float q = 0.f;
#pragma unroll
        for (int c = 0; c < 16; ++c)
            q += klred[(l * 16 + c) * 64 + t];
        float qm = q * (1.f / 131072.f);
        term += p * logf(p / qm) + (1.f - p) * logf((1.f - p) / (1.f - qm));
    }
#pragma unroll
    for (int off = 32; off > 0; off >>= 1)
        term += __shfl_down(term, off);
    if (t == 0)
        lossout[0] = 0.05f * tvred[0] / 8388608.f + 0.1f * term;
}

extern "C" void kernel_launch(void* const* d_in, const int* in_sizes, int n_in,
                              void* d_out, int out_size, void* d_ws, size_t ws_size,
                              hipStream_t stream) {
    (void)in_sizes; (void)n_in; (void)out_size; (void)ws_size;
    const float* x  = (const float*)d_in[0];
    const float* v1 = (const float*)d_in[2];
    const float* T1 = (const float*)d_in[3];
    const float* v2 = (const float*)d_in[4];
    const float* T2 = (const float*)d_in[5];
    const float* v3 = (const float*)d_in[6];
    const float* T3 = (const float*)d_in[7];
    const float* w1 = (const float*)d_in[8];
    const float* b1 = (const float*)d_in[9];
    const float* w2 = (const float*)d_in[10];
    const float* b2 = (const float*)d_in[11];
    const float* w3 = (const float*)d_in[12];
    const float* b3 = (const float*)d_in[13];
    const float* w4 = (const float*)d_in[14];
    const float* b4 = (const float*)d_in[15];
    float* out = (float*)d_out;

    float* W0 = (float*)d_ws;
    float* W1 = W0 + (size_t)NPLANES * PLANE;
    float* W2 = W1 + (size_t)NPLANES * PLANE;
    float* klpart = W2 + (size_t)NPLANES * PLANE; // [3][2048][64] = 393216 floats
    float* tvpart = klpart + 3 * 2048 * 64;        // [2048]
    float* klred  = tvpart + 2048;                  // [3][16][64] = 3072
    float* tvred  = klred + 3072;                   // [1]
    float* w3c = tvred + 64;                        // 784 floats
    float* w4p = w3c + 784;                         // 1024 floats
    float* x10buf = out;                            // reuse d_out region as x10 scratch

    prep_weights<<<4, 256, 0, stream>>>(w3, w4, w3c, w4p);
    // x1 (padded) -> W0
    conv1_kernel<<<dim3(4, 4, 128), 256, 0, stream>>>(x, w1, b1, W0);
    // KL1 partials; x9 = crop(ifwht(x6)) -> W1   (x6 itself never materialized)
    fwht_kernel_t<false><<<NPLANES, 256, 0, stream>>>(W0, v1, T1, nullptr, W1, klpart);
    // x10 -> d_out scratch
    conv7_kernel<<<dim3(4, 4, 128), 256, 0, stream>>>(W1, w2, b2, nullptr, x10buf);
    // KL2 partials; x18 -> W0
    fwht_kernel_t<false><<<NPLANES, 256, 0, stream>>>(x10buf, v2, T2, nullptr, W0, klpart + 131072);
    // x19 = convT3(x18) + x10 -> W2
    conv7_kernel<<<dim3(4, 4, 128), 256, 0, stream>>>(W0, w3c, b3, x10buf, W2);
    // KL3 partials; x27 = crop(ifwht(x24)) + x9 -> W0   (linearity of ifwht)
    fwht_kernel_t<true><<<NPLANES, 256, 0, stream>>>(W2, v3, T3, W1, W0, klpart + 2 * 131072);
    // out = convT4(x27) * x
    convt4_kernel<<<dim3(4, 4, 128), 256, 0, stream>>>(W0, w4p, b4, x, out);
    // TV partials on out
    tv_kernel<<<2048, 256, 0, stream>>>(out, tvpart);
    // stage-1 reduce + finalize
    reduce1_kernel<<<49, 256, 0, stream>>>(klpart, tvpart, klred, tvred);
    finalize2_kernel<<<1, 64, 0, stream>>>(klred, tvred, out + 8388608);
}

// Round 13
// 367.716 us; speedup vs baseline: 1.2163x; 1.0065x over previous
//
#include <hip/hip_runtime.h>
#include <math.h>

#define PLANE 16384   // 128*128
#define NPLANES 512   // B(128) * C(4)

// ---------------- in-register 2D FWHT-128x128 across a 512-thread block ----------------
// Thread (W = tid>>6 in [0,8), L = tid&63) holds v[g*4+c] = plane[h][w],
//   h = W*16 + (L>>5)*8 + g   (g in [0,8))   -> h bits: g=0-2, L5=3, W=4-6
//   w = (L&31)*4 + c          (c in [0,4))   -> w bits: c=0-1, L0-4=2-6
// 8 waves/plane -> 16 waves/CU (2 blocks/CU at 32KB LDS): 2x the latency hiding
// of the 4-wave variant.
__device__ __forceinline__ void fwht2d_reg512(float* __restrict__ v, float* __restrict__ xch,
                                              int W, int L) {
    // w bits 0-1 (reg bits 0-1): in-register
#pragma unroll
    for (int m = 1; m <= 2; m <<= 1) {
#pragma unroll
        for (int r = 0; r < 32; ++r) {
            if (!(r & m)) {
                int s = r | m;
                float a = v[r], b = v[s];
                v[r] = a + b; v[s] = a - b;
            }
        }
    }
    // w bits 2-6 (L bits 0-4) and h bit 3 (L bit 5): cross-lane shuffle stages
#pragma unroll
    for (int m = 1; m <= 32; m <<= 1) {
        float sg = (L & m) ? -1.f : 1.f;
#pragma unroll
        for (int r = 0; r < 32; ++r) {
            float p = __shfl_xor(v[r], m);
            v[r] = fmaf(sg, v[r], p);
        }
    }
    // h bits 0-2 (reg bits 2-4): in-register
#pragma unroll
    for (int m = 4; m <= 16; m <<= 1) {
#pragma unroll
        for (int r = 0; r < 32; ++r) {
            if (!(r & m)) {
                int s = r | m;
                float a = v[r], b = v[s];
                v[r] = a + b; v[s] = a - b;
            }
        }
    }
    // h bits 4-6 (wave index): 3 pairwise LDS stages x 2 reg-halves, conflict-free layout
#pragma unroll
    for (int mw = 1; mw <= 4; mw <<= 1) {
        int Wp = W ^ mw;
        float sg = (W & mw) ? -1.f : 1.f;
#pragma unroll
        for (int half = 0; half < 2; ++half) {
            __syncthreads();
#pragma unroll
            for (int j = 0; j < 16; ++j)
                xch[(j * 8 + W) * 64 + L] = v[half * 16 + j];
            __syncthreads();
#pragma unroll
            for (int j = 0; j < 16; ++j) {
                float p = xch[(j * 8 + Wp) * 64 + L];
                v[half * 16 + j] = fmaf(sg, v[half * 16 + j], p);
            }
        }
    }
}

// FWHT2 -> *v -> hard-thresh (KL partials) -> iFWHT2 -> (optional +addbuf) -> crop store
template <bool ADDPOST>
__global__ __launch_bounds__(512) void fwht_kernel_t(
    const float* __restrict__ in, const float* __restrict__ vmat,
    const float* __restrict__ tmat, const float* __restrict__ addbuf,
    float* __restrict__ outInv, float* __restrict__ klpart)  // [plane*8+W][64]
{
    __shared__ float xch[16 * 512]; // 32 KiB
    const int tid = threadIdx.x;
    const int W = tid >> 6, L = tid & 63;
    const int plane = blockIdx.x;
    const int hbase = W * 16 + ((L >> 5) << 3);
    const int wbase = (L & 31) << 2;
    const float* src = in + (size_t)plane * PLANE;

    float v[32];
#pragma unroll
    for (int g = 0; g < 8; ++g) {
        float4 t = *(const float4*)&src[(hbase + g) * 128 + wbase];
        v[4 * g] = t.x; v[4 * g + 1] = t.y; v[4 * g + 2] = t.z; v[4 * g + 3] = t.w;
    }

    fwht2d_reg512(v, xch, W, L);

    // pointwise: *vmat, hard-threshold, KL accumulate
    float ls0 = 0.f, ls1 = 0.f, ls2 = 0.f, ls3 = 0.f;
#pragma unroll
    for (int g = 0; g < 8; ++g) {
        int rowoff = (hbase + g) * 128 + wbase;
        float4 vm = *(const float4*)&vmat[rowoff];
        float4 tm = *(const float4*)&tmat[rowoff];
        float y0 = v[4 * g]     * vm.x;
        float y1 = v[4 * g + 1] * vm.y;
        float y2 = v[4 * g + 2] * vm.z;
        float y3 = v[4 * g + 3] * vm.w;
        y0 = (fabsf(y0) > fabsf(tm.x)) ? y0 : 0.f;
        y1 = (fabsf(y1) > fabsf(tm.y)) ? y1 : 0.f;
        y2 = (fabsf(y2) > fabsf(tm.z)) ? y2 : 0.f;
        y3 = (fabsf(y3) > fabsf(tm.w)) ? y3 : 0.f;
        ls0 += 1.f / (1.f + __expf(-fabsf(y0)));
        ls1 += 1.f / (1.f + __expf(-fabsf(y1)));
        ls2 += 1.f / (1.f + __expf(-fabsf(y2)));
        ls3 += 1.f / (1.f + __expf(-fabsf(y3)));
        v[4 * g] = y0; v[4 * g + 1] = y1; v[4 * g + 2] = y2; v[4 * g + 3] = y3;
    }
    // KL bins: bin = w%64 = (L&15)*4 + c; reduce the 4 lanes sharing (L&15), then one
    // coalesced float4 store per wave into a private partial row (NO atomics).
#pragma unroll
    for (int m = 16; m <= 32; m <<= 1) {
        ls0 += __shfl_xor(ls0, m);
        ls1 += __shfl_xor(ls1, m);
        ls2 += __shfl_xor(ls2, m);
        ls3 += __shfl_xor(ls3, m);
    }
    if (L < 16) {
        float4 o; o.x = ls0; o.y = ls1; o.z = ls2; o.w = ls3;
        *(float4*)&klpart[(size_t)(plane * 8 + W) * 64 + 4 * L] = o;
    }

    fwht2d_reg512(v, xch, W, L);

    // scale 1/16384, optional add (post-inverse, by linearity), crop to 122x122, store
    float* dst = outInv + (size_t)plane * PLANE;
    const float s = 1.f / 16384.f;
#pragma unroll
    for (int g = 0; g < 8; ++g) {
        int h = hbase + g;
        int rowoff = h * 128 + wbase;
        bool rv = h < 122;
        float4 ad = make_float4(0.f, 0.f, 0.f, 0.f);
        if (ADDPOST) ad = *(const float4*)&addbuf[(size_t)plane * PLANE + rowoff];
        float4 o;
        o.x = (rv && wbase + 0 < 122) ? fmaf(v[4 * g],     s, ad.x) : 0.f;
        o.y = (rv && wbase + 1 < 122) ? fmaf(v[4 * g + 1], s, ad.y) : 0.f;
        o.z = (rv && wbase + 2 < 122) ? fmaf(v[4 * g + 2], s, ad.z) : 0.f;
        o.w = (rv && wbase + 3 < 122) ? fmaf(v[4 * g + 3], s, ad.w) : 0.f;
        *(float4*)&dst[rowoff] = o;
    }
}

// ---------------- weight prep: canonicalize w3 (transposed 7x7) and w4 (convT 16x16 s2) ----------------
__global__ void prep_weights(const float* __restrict__ w3, const float* __restrict__ w4,
                             float* __restrict__ w3c, float* __restrict__ w4p)
{
    int tid = blockIdx.x * 256 + threadIdx.x;
    if (tid < 784) {
        int oc = tid / 196;
        int rem = tid - oc * 196;
        int ic = rem / 49;
        int k = rem - ic * 49;
        int kh = k / 7, kw = k - kh * 7;
        w3c[(oc * 4 + ic) * 49 + k] = w3[(ic * 4 + oc) * 49 + (6 - kh) * 7 + (6 - kw)];
    }
    if (tid < 1024) {
        // layout [ic:2][pa:1][pb:1][t:3][u:3]
        int u = tid & 7, t = (tid >> 3) & 7, pb = (tid >> 6) & 1, pa = (tid >> 7) & 1, ic = tid >> 8;
        int kh = 2 * t + (pa ? 0 : 1);
        int kw = 2 * u + (pb ? 0 : 1);
        w4p[tid] = w4[ic * 256 + kh * 16 + kw];
    }
}

// ---------------- conv1: 1->4, k16, s2, p1 : x[B,1,256,256] -> [B,4,128,128] padded ----------------
// Parity-split LDS tile kills the 16-way bank conflict of the stride-2 window read.
__global__ __launch_bounds__(256) void conv1_kernel(
    const float* __restrict__ x, const float* __restrict__ w1,
    const float* __restrict__ b1, float* __restrict__ out)
{
    __shared__ float tile[2][78][44];
    int tx = blockIdx.x, ty = blockIdx.y, b = blockIdx.z;
    int tid = threadIdx.x;
    const float* xp = x + (size_t)b * 65536;
    int r0g = ty * 64 - 1, c0g = tx * 64 - 1;
    for (int i = tid; i < 78 * 78; i += 256) {
        int rr = i / 78, cc = i - rr * 78;
        int gi = r0g + rr, gj = c0g + cc;
        float v = (gi >= 0 && gi < 256 && gj >= 0 && gj < 256) ? xp[gi * 256 + gj] : 0.f;
        tile[cc & 1][rr][cc >> 1] = v;
    }
    __syncthreads();
    int cg = tid & 7, r = tid >> 3;
    int B = cg * 4;
    float acc[4][4];
#pragma unroll
    for (int oc = 0; oc < 4; ++oc)
#pragma unroll
        for (int c = 0; c < 4; ++c) acc[oc][c] = 0.f;
#pragma unroll 1
    for (int kh = 0; kh < 16; ++kh) {
        float win[2][12];
        const float* te = &tile[0][2 * r + kh][B];
        const float* to = &tile[1][2 * r + kh][B];
#pragma unroll
        for (int k = 0; k < 3; ++k) {
            *(float4*)&win[0][4 * k] = *(const float4*)&te[4 * k];
            *(float4*)&win[1][4 * k] = *(const float4*)&to[4 * k];
        }
#pragma unroll
        for (int oc = 0; oc < 4; ++oc) {
            const float* wr = w1 + oc * 256 + kh * 16;
#pragma unroll
            for (int kw = 0; kw < 16; ++kw) {
                float wv = wr[kw];
                const float* wp8 = win[kw & 1];
                int q = kw >> 1;
#pragma unroll
                for (int c = 0; c < 4; ++c)
                    acc[oc][c] = fmaf(wp8[c + q], wv, acc[oc][c]);
            }
        }
    }
    int oh = ty * 32 + r;
    int owb = tx * 32 + B;
    bool rowv = oh < 122;
#pragma unroll
    for (int oc = 0; oc < 4; ++oc) {
        float bv = b1[oc];
        float4 res;
        res.x = (rowv && owb + 0 < 122) ? acc[oc][0] + bv : 0.f;
        res.y = (rowv && owb + 1 < 122) ? acc[oc][1] + bv : 0.f;
        res.z = (rowv && owb + 2 < 122) ? acc[oc][2] + bv : 0.f;
        res.w = (rowv && owb + 3 < 122) ? acc[oc][3] + bv : 0.f;
        *(float4*)&out[(((size_t)b * 4 + oc) << 14) + (oh << 7) + owb] = res;
    }
}

// ---------------- 7x7 conv, 4->4, pad 3, canonical weights [oc][ic][kh][kw], optional skip ----------------
__global__ __launch_bounds__(256) void conv7_kernel(
    const float* __restrict__ in, const float* __restrict__ w,
    const float* __restrict__ bias, const float* __restrict__ skip,
    float* __restrict__ out)
{
    __shared__ float tile[4][38][40];
    int tx = blockIdx.x, ty = blockIdx.y, b = blockIdx.z;
    int tid = threadIdx.x;
    int r0g = ty * 32 - 3, c0g = tx * 32 - 3;
    for (int i = tid; i < 4 * 38 * 38; i += 256) {
        int ic = i / 1444;
        int rem = i - ic * 1444;
        int rr = rem / 38, cc = rem - rr * 38;
        int gi = r0g + rr, gj = c0g + cc;
        float v = 0.f;
        if (gi >= 0 && gi < 128 && gj >= 0 && gj < 128)
            v = in[(((size_t)b * 4 + ic) << 14) + (gi << 7) + gj];
        tile[ic][rr][cc] = v;
    }
    __syncthreads();
    int cg = tid & 7, r = tid >> 3;
    int B = cg * 4;
    float acc[4][4];
#pragma unroll
    for (int oc = 0; oc < 4; ++oc)
#pragma unroll
        for (int c = 0; c < 4; ++c) acc[oc][c] = 0.f;
#pragma unroll 1
    for (int ic = 0; ic < 4; ++ic) {
#pragma unroll 1
        for (int kh = 0; kh < 7; ++kh) {
            float win[12];
            const float* trow = &tile[ic][r + kh][B];
#pragma unroll
            for (int k = 0; k < 3; ++k)
                *(float4*)&win[4 * k] = *(const float4*)&trow[4 * k];
#pragma unroll
            for (int oc = 0; oc < 4; ++oc) {
                const float* wr = w + (oc * 4 + ic) * 49 + kh * 7;
#pragma unroll
                for (int kw = 0; kw < 7; ++kw) {
                    float wv = wr[kw];
#pragma unroll
                    for (int c = 0; c < 4; ++c)
                        acc[oc][c] = fmaf(win[c + kw], wv, acc[oc][c]);
                }
            }
        }
    }
    int oh = ty * 32 + r;
    int owb = tx * 32 + B;
    bool rowv = oh < 122;
#pragma unroll
    for (int oc = 0; oc < 4; ++oc) {
        size_t o = (((size_t)b * 4 + oc) << 14) + (oh << 7) + owb;
        float4 sv = make_float4(0.f, 0.f, 0.f, 0.f);
        if (skip) sv = *(const float4*)&skip[o];
        float bv = bias[oc];
        float4 res;
        res.x = (rowv && owb + 0 < 122) ? acc[oc][0] + bv + sv.x : 0.f;
        res.y = (rowv && owb + 1 < 122) ? acc[oc][1] + bv + sv.y : 0.f;
        res.z = (rowv && owb + 2 < 122) ? acc[oc][2] + bv + sv.z : 0.f;
        res.w = (rowv && owb + 3 < 122) ? acc[oc][3] + bv + sv.w : 0.f;
        *(float4*)&out[o] = res;
    }
}

// ---------------- convT4: 4->1, k16, s2, p1, parity-decomposed; then * x ----------------
#define CT_HALF(T, ROW, PA)                                                    \
    _Pragma("unroll")                                                          \
    for (int pb = 0; pb < 2; ++pb) {                                           \
        const float* w8 = wp + (((ic * 2 + (PA)) * 2 + pb) * 8 + (T)) * 8;     \
        _Pragma("unroll")                                                      \
        for (int u = 0; u < 8; ++u) {                                          \
            float wv = w8[u];                                                  \
            _Pragma("unroll")                                                  \
            for (int c = 0; c < 4; ++c)                                        \
                acc[PA][pb][c] = fmaf(ROW[8 + c + pb - u], wv, acc[PA][pb][c]);\
        }                                                                      \
    }

__global__ __launch_bounds__(256) void convt4_kernel(
    const float* __restrict__ in, const float* __restrict__ wp,
    const float* __restrict__ bias, const float* __restrict__ xin,
    float* __restrict__ out)
{
    __shared__ float tile[4][40][44];
    int tx = blockIdx.x, ty = blockIdx.y, b = blockIdx.z;
    int tid = threadIdx.x;
    int A0 = ty * 32, B0 = tx * 32;
    int r0g = A0 - 7, c0g = B0 - 8;
    for (int i = tid; i < 4 * 40 * 44; i += 256) {
        int ic = i / 1760;
        int rem = i - ic * 1760;
        int rr = rem / 44, cc = rem - rr * 44;
        int gi = r0g + rr, gj = c0g + cc;
        float v = 0.f;
        if (gi >= 0 && gi < 128 && gj >= 0 && gj < 128)
            v = in[(((size_t)b * 4 + ic) << 14) + (gi << 7) + gj];
        tile[ic][rr][cc] = v;
    }
    __syncthreads();
    int cg = tid & 7, ra = tid >> 3;
    float acc[2][2][4];
#pragma unroll
    for (int pa = 0; pa < 2; ++pa)
#pragma unroll
        for (int pb = 0; pb < 2; ++pb)
#pragma unroll
            for (int c = 0; c < 4; ++c) acc[pa][pb][c] = 0.f;
#pragma unroll 1
    for (int ic = 0; ic < 4; ++ic) {
        float bufA[16], bufB[16];
#pragma unroll
        for (int k = 0; k < 4; ++k)
            *(float4*)&bufB[4 * k] = *(const float4*)&tile[ic][ra + 8][4 * cg + 4 * k];
#pragma unroll 1
        for (int t2 = 0; t2 < 8; t2 += 2) {
#pragma unroll
            for (int k = 0; k < 4; ++k)
                *(float4*)&bufA[4 * k] = *(const float4*)&tile[ic][ra + 7 - t2][4 * cg + 4 * k];
            CT_HALF(t2, bufA, 0)
            CT_HALF(t2, bufB, 1)
#pragma unroll
            for (int k = 0; k < 4; ++k)
                *(float4*)&bufB[4 * k] = *(const float4*)&tile[ic][ra + 6 - t2][4 * cg + 4 * k];
            CT_HALF(t2 + 1, bufB, 0)
            CT_HALF(t2 + 1, bufA, 1)
        }
    }
    int oh0 = 2 * (A0 + ra);
    int owb = 2 * (B0 + 4 * cg);
    float bv = bias[0];
#pragma unroll
    for (int pa = 0; pa < 2; ++pa) {
        size_t o = (size_t)b * 65536 + (size_t)(oh0 + pa) * 256 + owb;
        float4 x0 = *(const float4*)&xin[o];
        float4 x1 = *(const float4*)&xin[o + 4];
        float4 r0, r1;
        r0.x = (acc[pa][0][0] + bv) * x0.x;
        r0.y = (acc[pa][1][0] + bv) * x0.y;
        r0.z = (acc[pa][0][1] + bv) * x0.z;
        r0.w = (acc[pa][1][1] + bv) * x0.w;
        r1.x = (acc[pa][0][2] + bv) * x1.x;
        r1.y = (acc[pa][1][2] + bv) * x1.y;
        r1.z = (acc[pa][0][3] + bv) * x1.z;
        r1.w = (acc[pa][1][3] + bv) * x1.w;
        *(float4*)&out[o] = r0;
        *(float4*)&out[o + 4] = r1;
    }
}

// ---------------- TV loss (vectorized, per-block partial, no atomics) ----------------
__global__ __launch_bounds__(256) void tv_kernel(
    const float* __restrict__ out, float* __restrict__ tvpart)
{
    const float4* out4 = (const float4*)out;
    __shared__ float red[256];
    int tid = threadIdx.x;
    float local = 0.f;
    const int total4 = 128 * 65536 / 4;
    for (int i4 = blockIdx.x * 256 + tid; i4 < total4; i4 += gridDim.x * 256) {
        float4 a = out4[i4];
        int i = i4 << 2;
        local += fabsf(a.y - a.x) + fabsf(a.z - a.y) + fabsf(a.w - a.z);
        if ((i & 255) != 252) local += fabsf(out[i + 4] - a.w);
        if ((i & 65535) < 65280) {
            float4 c = out4[i4 + 64];
            local += fabsf(c.x - a.x) + fabsf(c.y - a.y) + fabsf(c.z - a.z) + fabsf(c.w - a.w);
        }
    }
    red[tid] = local;
    __syncthreads();
    for (int s = 128; s > 0; s >>= 1) {
        if (tid < s) red[tid] += red[tid + s];
        __syncthreads();
    }
    if (tid == 0) tvpart[blockIdx.x] = red[0];
}

// ---------------- stage-1 reduce: KL partials [3][4096][64] -> [3][16][64]; TV [2048] -> [1] ----------------
__global__ __launch_bounds__(256) void reduce1_kernel(
    const float* __restrict__ klpart, const float* __restrict__ tvpart,
    float* __restrict__ klred, float* __restrict__ tvred)
{
    int bid = blockIdx.x;
    int tid = threadIdx.x;
    if (bid < 48) {
        int layer = bid >> 4, chunk = bid & 15;
        int sub = tid >> 6, t = tid & 63;
        const float* base = klpart + (size_t)layer * 262144 + (size_t)chunk * 256 * 64;
        float s = 0.f;
        for (int r = sub; r < 256; r += 4)
            s += base[r * 64 + t];
        __shared__ float red[4][64];
        red[sub][t] = s;
        __syncthreads();
        if (tid < 64)
            klred[(layer * 16 + chunk) * 64 + tid] =
                red[0][tid] + red[1][tid] + red[2][tid] + red[3][tid];
    } else {
        __shared__ float red[256];
        float s = 0.f;
        for (int i = tid; i < 2048; i += 256) s += tvpart[i];
        red[tid] = s;
        __syncthreads();
        for (int st = 128; st > 0; st >>= 1) {
            if (tid < st) red[tid] += red[tid + st];
            __syncthreads();
        }
        if (tid == 0) tvred[0] = red[0];
    }
}

// ---------------- stage-2 finalize: [3][16][64] + tv -> loss ----------------
__global__ __launch_bounds__(64) void finalize2_kernel(
    const float* __restrict__ klred, const float* __restrict__ tvred,
    float* __restrict__ lossout)
{
    int t = threadIdx.x;
    float p = 1.f / (1.f + __expf(-0.001f));
    float term = 0.f;
#pragma unroll
    for (int l = 0; l < 3; ++l) {
        float q = 0.f;
#pragma unroll
        for (int c = 0; c < 16; ++c)
            q += klred[(l * 16 + c) * 64 + t];
        float qm = q * (1.f / 131072.f);
        term += p * logf(p / qm) + (1.f - p) * logf((1.f - p) / (1.f - qm));
    }
#pragma unroll
    for (int off = 32; off > 0; off >>= 1)
        term += __shfl_down(term, off);
    if (t == 0)
        lossout[0] = 0.05f * tvred[0] / 8388608.f + 0.1f * term;
}

extern "C" void kernel_launch(void* const* d_in, const int* in_sizes, int n_in,
                              void* d_out, int out_size, void* d_ws, size_t ws_size,
                              hipStream_t stream) {
    (void)in_sizes; (void)n_in; (void)out_size; (void)ws_size;
    const float* x  = (const float*)d_in[0];
    const float* v1 = (const float*)d_in[2];
    const float* T1 = (const float*)d_in[3];
    const float* v2 = (const float*)d_in[4];
    const float* T2 = (const float*)d_in[5];
    const float* v3 = (const float*)d_in[6];
    const float* T3 = (const float*)d_in[7];
    const float* w1 = (const float*)d_in[8];
    const float* b1 = (const float*)d_in[9];
    const float* w2 = (const float*)d_in[10];
    const float* b2 = (const float*)d_in[11];
    const float* w3 = (const float*)d_in[12];
    const float* b3 = (const float*)d_in[13];
    const float* w4 = (const float*)d_in[14];
    const float* b4 = (const float*)d_in[15];
    float* out = (float*)d_out;

    float* W0 = (float*)d_ws;
    float* W1 = W0 + (size_t)NPLANES * PLANE;
    float* W2 = W1 + (size_t)NPLANES * PLANE;
    float* klpart = W2 + (size_t)NPLANES * PLANE; // [3][4096][64] = 786432 floats
    float* tvpart = klpart + 3 * 4096 * 64;        // [2048]
    float* klred  = tvpart + 2048;                  // [3][16][64] = 3072
    float* tvred  = klred + 3072;                   // [1]
    float* w3c = tvred + 64;                        // 784 floats
    float* w4p = w3c + 784;                         // 1024 floats
    float* x10buf = out;                            // reuse d_out region as x10 scratch

    prep_weights<<<4, 256, 0, stream>>>(w3, w4, w3c, w4p);
    // x1 (padded) -> W0
    conv1_kernel<<<dim3(4, 4, 128), 256, 0, stream>>>(x, w1, b1, W0);
    // KL1 partials; x9 = crop(ifwht(x6)) -> W1   (x6 itself never materialized)
    fwht_kernel_t<false><<<NPLANES, 512, 0, stream>>>(W0, v1, T1, nullptr, W1, klpart);
    // x10 -> d_out scratch
    conv7_kernel<<<dim3(4, 4, 128), 256, 0, stream>>>(W1, w2, b2, nullptr, x10buf);
    // KL2 partials; x18 -> W0
    fwht_kernel_t<false><<<NPLANES, 512, 0, stream>>>(x10buf, v2, T2, nullptr, W0, klpart + 262144);
    // x19 = convT3(x18) + x10 -> W2
    conv7_kernel<<<dim3(4, 4, 128), 256, 0, stream>>>(W0, w3c, b3, x10buf, W2);
    // KL3 partials; x27 = crop(ifwht(x24)) + x9 -> W0   (linearity of ifwht)
    fwht_kernel_t<true><<<NPLANES, 512, 0, stream>>>(W2, v3, T3, W1, W0, klpart + 2 * 262144);
    // out = convT4(x27) * x
    convt4_kernel<<<dim3(4, 4, 128), 256, 0, stream>>>(W0, w4p, b4, x, out);
    // TV partials on out
    tv_kernel<<<2048, 256, 0, stream>>>(out, tvpart);
    // stage-1 reduce + finalize
    reduce1_kernel<<<49, 256, 0, stream>>>(klpart, tvpart, klred, tvred);
    finalize2_kernel<<<1, 64, 0, stream>>>(klred, tvred, out + 8388608);
}